// Round 1
// baseline (169.066 us; speedup 1.0000x reference)
//
#include <hip/hip_runtime.h>

// Problem constants (match reference)
constexpr int T     = 4;
constexpr int NROWS = 1000000;
constexpr int D     = 4;          // row = float4
constexpr int B     = 16384;
constexpr int TOTAL = 16384 * 50; // 819200 lookups per table
constexpr int CHUNK = 16;         // lookups per thread; TOTAL % CHUNK == 0

__global__ __launch_bounds__(256)
void init_out_kernel(float* __restrict__ out, const float* __restrict__ bias) {
    int j = blockIdx.x * blockDim.x + threadIdx.x;
    if (j < T * B) out[j] = bias[0];
}

__global__ __launch_bounds__(256)
void pool_kernel(const float4* __restrict__ tables,   // [T*NROWS] float4 rows
                 const float4* __restrict__ Wp,       // [1] float4
                 const int*    __restrict__ indices,  // [T*TOTAL]
                 const int*    __restrict__ segids,   // [T*TOTAL] sorted per table
                 float*        __restrict__ out)      // [T*B]
{
    const float4 w = Wp[0];

    long long chunk = (long long)blockIdx.x * blockDim.x + threadIdx.x;
    long long base  = chunk * CHUNK;
    if (base >= (long long)T * TOTAL) return;

    const int t     = (int)(base / TOTAL);
    const int local = (int)(base % TOTAL);

    // 64-byte aligned: local is a multiple of CHUNK=16, TOTAL % 4 == 0
    const int4*  idx4 = (const int4*)(indices + (long long)t * TOTAL + local);
    const int4*  seg4 = (const int4*)(segids  + (long long)t * TOTAL + local);
    const float4* tbl = tables + (long long)t * NROWS;
    float* outt = out + t * B;

    float acc = 0.0f;
    int   cur = -1;

    #pragma unroll
    for (int kk = 0; kk < CHUNK / 4; ++kk) {
        const int4 s4 = seg4[kk];
        const int4 i4 = idx4[kk];

        // Issue all 4 gathers up front (independent of the run-length chain)
        const float4 r0 = tbl[i4.x];
        const float4 r1 = tbl[i4.y];
        const float4 r2 = tbl[i4.z];
        const float4 r3 = tbl[i4.w];

        const float v0 = r0.x * w.x + r0.y * w.y + r0.z * w.z + r0.w * w.w;
        const float v1 = r1.x * w.x + r1.y * w.y + r1.z * w.z + r1.w * w.w;
        const float v2 = r2.x * w.x + r2.y * w.y + r2.z * w.z + r2.w * w.w;
        const float v3 = r3.x * w.x + r3.y * w.y + r3.z * w.z + r3.w * w.w;

        const int ss[4] = {s4.x, s4.y, s4.z, s4.w};
        const float vv[4] = {v0, v1, v2, v3};

        #pragma unroll
        for (int j = 0; j < 4; ++j) {
            if (ss[j] != cur) {
                if (cur >= 0) atomicAdd(&outt[cur], acc);
                acc = 0.0f;
                cur = ss[j];
            }
            acc += vv[j];
        }
    }
    if (cur >= 0) atomicAdd(&outt[cur], acc);
}

extern "C" void kernel_launch(void* const* d_in, const int* in_sizes, int n_in,
                              void* d_out, int out_size, void* d_ws, size_t ws_size,
                              hipStream_t stream) {
    const float4* tables  = (const float4*)d_in[0];  // [T, N, D] f32
    const float4* W       = (const float4*)d_in[1];  // [1, D]   f32
    const float*  bias    = (const float*)d_in[2];   // [1]      f32
    const int*    indices = (const int*)d_in[3];     // [T, TOTAL]
    const int*    segids  = (const int*)d_in[4];     // [T, TOTAL]
    float*        out     = (float*)d_out;           // [T*B] f32

    // 1) out[:] = bias (empty bags must yield exactly b)
    {
        int n = T * B;
        int blocks = (n + 255) / 256;
        init_out_kernel<<<blocks, 256, 0, stream>>>(out, bias);
    }

    // 2) fused gather + segmented pool + Linear(4->1)
    {
        long long nchunks = (long long)T * TOTAL / CHUNK; // 204800
        int blocks = (int)((nchunks + 255) / 256);        // 800
        pool_kernel<<<blocks, 256, 0, stream>>>(tables, W, indices, segids, out);
    }
}

// Round 2
// 157.582 us; speedup vs baseline: 1.0729x; 1.0729x over previous
//
#include <hip/hip_runtime.h>

// Problem constants (match reference)
constexpr int T     = 4;
constexpr int NROWS = 1000000;
constexpr int B     = 16384;
constexpr int TOTAL = 16384 * 50; // 819200 lookups per table
constexpr int CHUNK = 8;          // lookups per thread; TOTAL % CHUNK == 0

__global__ __launch_bounds__(256)
void init_out_kernel(float* __restrict__ out, const float* __restrict__ bias) {
    int j = blockIdx.x * blockDim.x + threadIdx.x;
    if (j < T * B) out[j] = bias[0];
}

// p[t*NROWS + r] = dot(table[t][r], W)  — streaming, BW-bound
__global__ __launch_bounds__(256)
void row_dot_kernel(const float4* __restrict__ tables,
                    const float4* __restrict__ Wp,
                    float* __restrict__ p) {
    const float4 w = Wp[0];
    int i = blockIdx.x * blockDim.x + threadIdx.x;
    if (i < T * NROWS) {
        const float4 r = tables[i];
        p[i] = r.x * w.x + r.y * w.y + r.z * w.z + r.w * w.w;
    }
}

// Gather 4-byte precomputed dots, run-length accumulate over sorted segment
// ids, flush via atomicAdd on segment change / thread end.
__global__ __launch_bounds__(256)
void pool_p_kernel(const float* __restrict__ p,        // [T*NROWS]
                   const int*   __restrict__ indices,  // [T*TOTAL]
                   const int*   __restrict__ segids,   // [T*TOTAL] sorted per table
                   float*       __restrict__ out)      // [T*B]
{
    int tid  = blockIdx.x * blockDim.x + threadIdx.x;
    int base = tid * CHUNK;
    if (base >= T * TOTAL) return;

    const int t     = base / TOTAL;
    const int local = base % TOTAL;

    const int4* idx4 = (const int4*)(indices + t * TOTAL + local); // 32B aligned
    const int4* seg4 = (const int4*)(segids  + t * TOTAL + local);
    const float* pt  = p + t * NROWS;
    float* outt      = out + t * B;

    const int4 ia = idx4[0], ib = idx4[1];
    const int4 sa = seg4[0], sb = seg4[1];

    const int ix[8] = {ia.x, ia.y, ia.z, ia.w, ib.x, ib.y, ib.z, ib.w};
    const int ss[8] = {sa.x, sa.y, sa.z, sa.w, sb.x, sb.y, sb.z, sb.w};

    // Issue all 8 independent gathers before the serial scan
    float v[8];
    #pragma unroll
    for (int j = 0; j < 8; ++j) v[j] = pt[ix[j]];

    float acc = 0.0f;
    int   cur = ss[0];
    #pragma unroll
    for (int j = 0; j < 8; ++j) {
        if (ss[j] != cur) {
            atomicAdd(&outt[cur], acc);
            acc = 0.0f;
            cur = ss[j];
        }
        acc += v[j];
    }
    atomicAdd(&outt[cur], acc);
}

// Fallback (no workspace): direct 16B-row gather version from round 1
__global__ __launch_bounds__(256)
void pool_direct_kernel(const float4* __restrict__ tables,
                        const float4* __restrict__ Wp,
                        const int*    __restrict__ indices,
                        const int*    __restrict__ segids,
                        float*        __restrict__ out)
{
    const float4 w = Wp[0];
    int tid  = blockIdx.x * blockDim.x + threadIdx.x;
    int base = tid * CHUNK;
    if (base >= T * TOTAL) return;

    const int t     = base / TOTAL;
    const int local = base % TOTAL;

    const int4* idx4 = (const int4*)(indices + t * TOTAL + local);
    const int4* seg4 = (const int4*)(segids  + t * TOTAL + local);
    const float4* tbl = tables + (long long)t * NROWS;
    float* outt = out + t * B;

    const int4 ia = idx4[0], ib = idx4[1];
    const int4 sa = seg4[0], sb = seg4[1];
    const int ix[8] = {ia.x, ia.y, ia.z, ia.w, ib.x, ib.y, ib.z, ib.w};
    const int ss[8] = {sa.x, sa.y, sa.z, sa.w, sb.x, sb.y, sb.z, sb.w};

    float v[8];
    #pragma unroll
    for (int j = 0; j < 8; ++j) {
        const float4 r = tbl[ix[j]];
        v[j] = r.x * w.x + r.y * w.y + r.z * w.z + r.w * w.w;
    }

    float acc = 0.0f;
    int   cur = ss[0];
    #pragma unroll
    for (int j = 0; j < 8; ++j) {
        if (ss[j] != cur) {
            atomicAdd(&outt[cur], acc);
            acc = 0.0f;
            cur = ss[j];
        }
        acc += v[j];
    }
    atomicAdd(&outt[cur], acc);
}

extern "C" void kernel_launch(void* const* d_in, const int* in_sizes, int n_in,
                              void* d_out, int out_size, void* d_ws, size_t ws_size,
                              hipStream_t stream) {
    const float4* tables  = (const float4*)d_in[0];  // [T, N, 4] f32
    const float4* W       = (const float4*)d_in[1];  // [1, 4]   f32
    const float*  bias    = (const float*)d_in[2];   // [1]      f32
    const int*    indices = (const int*)d_in[3];     // [T, TOTAL]
    const int*    segids  = (const int*)d_in[4];     // [T, TOTAL]
    float*        out     = (float*)d_out;           // [T*B] f32

    // out[:] = bias (empty bags yield exactly b)
    {
        int n = T * B;
        init_out_kernel<<<(n + 255) / 256, 256, 0, stream>>>(out, bias);
    }

    const size_t p_bytes = (size_t)T * NROWS * sizeof(float); // 16 MB
    const int nthreads   = T * TOTAL / CHUNK;                 // 409,600
    const int pool_blocks = (nthreads + 255) / 256;           // 1600

    if (ws_size >= p_bytes) {
        float* p = (float*)d_ws;
        {
            int n = T * NROWS;
            row_dot_kernel<<<(n + 255) / 256, 256, 0, stream>>>(tables, W, p);
        }
        pool_p_kernel<<<pool_blocks, 256, 0, stream>>>(p, indices, segids, out);
    } else {
        pool_direct_kernel<<<pool_blocks, 256, 0, stream>>>(tables, W, indices, segids, out);
    }
}